// Round 9
// baseline (35.952 us; speedup 1.0000x reference)
//
#include <hip/hip_runtime.h>
#include <stdint.h>

typedef int i32x4 __attribute__((ext_vector_type(4)));
typedef float f32x4 __attribute__((ext_vector_type(4)));
typedef unsigned int u32x2 __attribute__((ext_vector_type(2)));

#define B_DIM 512
#define IN_DIM 1024
#define OUT_DIM 1024
#define TM 64
#define TN 32
#define KC 128                       // original-k per chunk (8 chunks)
#define APL (B_DIM * IN_DIM)         // 524288 bytes per x i8 plane
#define WPL (OUT_DIM * IN_DIM)       // 1048576 bytes per w i8 plane

static __device__ __forceinline__ unsigned long long expx(int i) {
    return 0x9E3779B97F4A7C15ull * (unsigned long long)(2 * i + 1);
}
static __device__ __forceinline__ unsigned long long expw(int i) {
    return 0xBF58476D1CE4E5B9ull * (unsigned long long)(2 * i + 1);
}

// magic-quant 4 floats -> packed hi-byte dword + centered-lo-byte dword.
// t = RN(v*4096 + 2^23+2^22+128): ulp=1, single round, half-even.
// mantissa byte0 = (q+128)&255 -> ^0x80 = centered lo in [-128,127]
// mantissa byte1 = (q+128)>>8 & 255 = hi   (q = 256*hi + lo exactly)
static __device__ __forceinline__ void qpack4(const f32x4 v, unsigned& hw, unsigned& lw) {
    const float MAGIC = 12583040.0f;         // 2^23 + 2^22 + 128
    unsigned tb0 = __builtin_bit_cast(unsigned, fmaf(v[0], 4096.0f, MAGIC));
    unsigned tb1 = __builtin_bit_cast(unsigned, fmaf(v[1], 4096.0f, MAGIC));
    unsigned tb2 = __builtin_bit_cast(unsigned, fmaf(v[2], 4096.0f, MAGIC));
    unsigned tb3 = __builtin_bit_cast(unsigned, fmaf(v[3], 4096.0f, MAGIC));
    unsigned p01h = __builtin_amdgcn_perm(tb1, tb0, 0x00000501u);
    unsigned p23h = __builtin_amdgcn_perm(tb3, tb2, 0x00000501u);
    hw = __builtin_amdgcn_perm(p23h, p01h, 0x05040100u);
    unsigned p01l = __builtin_amdgcn_perm(tb1, tb0, 0x00000400u);
    unsigned p23l = __builtin_amdgcn_perm(tb3, tb2, 0x00000400u);
    lw = __builtin_amdgcn_perm(p23l, p01l, 0x05040100u) ^ 0x80808080u;
}

// Single kernel, 256 blocks x 512 threads (all co-resident, 1-2 blocks/CU).
// Phase P (producer): each block quantizes x rows [2b,2b+2) and w rows
//   [4b,4b+4) into shared i8 hi/lo planes in d_ws, then release-fence +
//   per-block MAGIC flag (agent scope).
// Phase C (consumer): poll the 40 flags covering this block's 64x1024 A and
//   32x1024 B slices, acquire-fence (L2 inv), then 8-chunk double-buffered
//   global_load_lds i8 GEMM (exact hh/mid/ll int8 MFMA) + exact requantize
//   + bias.
// Replay safety: flags/data from a previous identical call are bit-identical
// (pure function of inputs), so stale-flag skip-wait reads are correct.
__global__ __launch_bounds__(512, 1) void fused_kernel(const float* __restrict__ x,
                                                       const float* __restrict__ w,
                                                       const float* __restrict__ bias,
                                                       float* __restrict__ out,
                                                       signed char* __restrict__ X8,
                                                       signed char* __restrict__ W8,
                                                       unsigned long long* __restrict__ xf,
                                                       unsigned long long* __restrict__ wf) {
    __shared__ signed char sA[2][16384];   // [buf][plane*8192 + row*128 + b]
    __shared__ signed char sB[2][8192];    // [buf][plane*4096 + row*128 + b]

    int b = blockIdx.x;
    int t = threadIdx.x;

    // ---- produce x sliver: rows 2b + (t>>8), 256 threads/row x f32x4 ----
    {
        int r = 2 * b + (t >> 8);
        int c4 = (t & 255) * 4;
        f32x4 v = *(const f32x4*)(x + (size_t)r * IN_DIM + c4);
        unsigned hw, lw;
        qpack4(v, hw, lw);
        *(unsigned*)(X8 + (size_t)r * IN_DIM + c4) = hw;
        *(unsigned*)(X8 + APL + (size_t)r * IN_DIM + c4) = lw;
    }
    // ---- produce w sliver: rows 4b + (t>>7), 128 threads/row x 8 f32 ----
    {
        int r = 4 * b + (t >> 7);
        int c8 = (t & 127) * 8;
        const f32x4* p = (const f32x4*)(w + (size_t)r * IN_DIM + c8);
        unsigned hw0, lw0, hw1, lw1;
        qpack4(p[0], hw0, lw0);
        qpack4(p[1], hw1, lw1);
        u32x2 hv = {hw0, hw1}, lv = {lw0, lw1};
        *(u32x2*)(W8 + (size_t)r * IN_DIM + c8) = hv;
        *(u32x2*)(W8 + WPL + (size_t)r * IN_DIM + c8) = lv;
    }
    __syncthreads();                       // all block stores drained to L2
    if (t == 0) {
        __builtin_amdgcn_fence(__ATOMIC_RELEASE, "agent");   // L2 writeback
        __hip_atomic_store(&xf[b], expx(b), __ATOMIC_RELAXED, __HIP_MEMORY_SCOPE_AGENT);
        __hip_atomic_store(&wf[b], expw(b), __ATOMIC_RELAXED, __HIP_MEMORY_SCOPE_AGENT);
    }

    // ---- consumer mapping: XCD (b&7) owns n-blocks 4x..4x+3 ----
    int nblk = (b & 7) * 4 + ((b >> 3) & 3);
    int mblk = b >> 5;
    int m0 = mblk * TM, n0 = nblk * TN;

    // ---- wait for the 32 x-producers and 8 w-producers of our slices ----
    if (t < 32) {
        int i = mblk * 32 + t;
        while (__hip_atomic_load(&xf[i], __ATOMIC_RELAXED, __HIP_MEMORY_SCOPE_AGENT) != expx(i))
            __builtin_amdgcn_s_sleep(1);
    } else if (t < 40) {
        int i = nblk * 8 + (t - 32);
        while (__hip_atomic_load(&wf[i], __ATOMIC_RELAXED, __HIP_MEMORY_SCOPE_AGENT) != expw(i))
            __builtin_amdgcn_s_sleep(1);
    }
    __syncthreads();
    __builtin_amdgcn_fence(__ATOMIC_ACQUIRE, "agent");   // invalidate stale L1/L2

    int lane = t & 63;
    int wv = t >> 6;            // 8 waves: 4 m-quadrants x 2 n-quadrants
    int wm = wv >> 1, wn = wv & 1;

    // ---- i8 staging via global_load_lds, pre-swizzled source, linear dest ----
    auto stage = [&](int c, int buf) {
        {
            int row = t >> 3, s = t & 7;
            const signed char* g0 = X8 + (size_t)(m0 + row) * IN_DIM + c * KC
                                       + ((s ^ (row & 7)) * 16);
            __builtin_amdgcn_global_load_lds(
                (const __attribute__((address_space(1))) void*)g0,
                (__attribute__((address_space(3))) void*)&sA[buf][t * 16], 16, 0, 0);
            __builtin_amdgcn_global_load_lds(
                (const __attribute__((address_space(1))) void*)(g0 + APL),
                (__attribute__((address_space(3))) void*)&sA[buf][8192 + t * 16], 16, 0, 0);
        }
        {
            int p = t >> 8, rem = t & 255;
            int row = rem >> 3, s = rem & 7;
            const signed char* g = W8 + (size_t)p * WPL + (size_t)(n0 + row) * IN_DIM
                                      + c * KC + ((s ^ (row & 7)) * 16);
            __builtin_amdgcn_global_load_lds(
                (const __attribute__((address_space(1))) void*)g,
                (__attribute__((address_space(3))) void*)&sB[buf][p * 4096 + rem * 16], 16, 0, 0);
        }
    };

    i32x4 hh = {}, mid = {}, ll = {};
    int arow = wm * 16 + (lane & 15);
    int brow = wn * 16 + (lane & 15);

    auto compute = [&](int buf) {
        __builtin_amdgcn_s_setprio(1);
#pragma unroll
        for (int k4 = 0; k4 < 2; ++k4) {
            int slot = ((k4 * 4 + (lane >> 4)) ^ (lane & 7)) * 16;  // arow&7==brow&7==lane&7
            i32x4 a0 = *(const i32x4*)&sA[buf][arow * 128 + slot];
            i32x4 a1 = *(const i32x4*)&sA[buf][8192 + arow * 128 + slot];
            i32x4 b0 = *(const i32x4*)&sB[buf][brow * 128 + slot];
            i32x4 b1 = *(const i32x4*)&sB[buf][4096 + brow * 128 + slot];
            hh  = __builtin_amdgcn_mfma_i32_16x16x64_i8(a0, b0, hh, 0, 0, 0);
            mid = __builtin_amdgcn_mfma_i32_16x16x64_i8(a0, b1, mid, 0, 0, 0);
            mid = __builtin_amdgcn_mfma_i32_16x16x64_i8(a1, b0, mid, 0, 0, 0);
            ll  = __builtin_amdgcn_mfma_i32_16x16x64_i8(a1, b1, ll, 0, 0, 0);
        }
        __builtin_amdgcn_s_setprio(0);
    };

    stage(0, 0);
    __syncthreads();
#pragma unroll
    for (int c = 0; c < 8; ++c) {
        if (c < 7) stage(c + 1, (c & 1) ^ 1);   // loads in flight during MFMA
        compute(c & 1);
        if (c < 7) __syncthreads();             // drains vmcnt: next chunk ready
    }

    // ---- epilogue: exact combine, requantize, bias ----
    // C/D layout: col = lane&15, row = (lane>>4)*4 + j
    int grow0 = m0 + wm * 16 + ((lane >> 4) << 2);
    int gcol = n0 + wn * 16 + (lane & 15);
    float bv = bias[gcol];
#pragma unroll
    for (int j = 0; j < 4; ++j) {
        int s = hh[j] * 65536 + mid[j] * 256 + ll[j];   // exact int32 acc
        double q = rint((double)s * 0x1p-12);           // exact round(acc*2^-12)
        q = q < -32768.0 ? -32768.0 : (q > 32767.0 ? 32767.0 : q);
        out[(size_t)(grow0 + j) * OUT_DIM + gcol] = (float)(q * 0x1p-12) + bv;
    }
}

extern "C" void kernel_launch(void* const* d_in, const int* in_sizes, int n_in,
                              void* d_out, int out_size, void* d_ws, size_t ws_size,
                              hipStream_t stream) {
    const float* x = (const float*)d_in[0];
    const float* w = (const float*)d_in[1];
    const float* bias = (const float*)d_in[2];
    float* out = (float*)d_out;

    signed char* X8 = (signed char*)d_ws;                                  // 1 MB
    signed char* W8 = (signed char*)d_ws + (1u << 20);                     // 2 MB
    unsigned long long* xf = (unsigned long long*)((char*)d_ws + (3u << 20));          // 2 KB
    unsigned long long* wf = (unsigned long long*)((char*)d_ws + (3u << 20) + 4096);   // 2 KB

    fused_kernel<<<256, 512, 0, stream>>>(x, w, bias, out, X8, W8, xf, wf);
}

// Round 10
// 11.730 us; speedup vs baseline: 3.0650x; 3.0650x over previous
//
#include <hip/hip_runtime.h>
#include <stdint.h>

typedef int i32x4 __attribute__((ext_vector_type(4)));
typedef float f32x4 __attribute__((ext_vector_type(4)));
typedef unsigned int u32x2 __attribute__((ext_vector_type(2)));
typedef unsigned int u32x4 __attribute__((ext_vector_type(4)));

#define B_DIM 512
#define IN_DIM 1024
#define OUT_DIM 1024
#define TM 64
#define TN 32
#define KC 128          // original-k elements per chunk (8 chunks)

// Single fused kernel, 512 threads (8 waves), 256 blocks (1/CU, 2 waves/SIMD).
// f32 -> int16 -> hi/lo i8 planes via one magic-fma per element, byte-packed
// with v_perm, staged in XOR-swizzled double-buffered LDS, exact int8 MFMA
// GEMM (hh/mid/ll paths), exact integer requantize + bias.
//
// Schedule: 8 K-chunks, depth-2 register prefetch, quant/ds_write of chunk
// c+1 overlapped with MFMA of chunk c, s_setprio around MFMA clusters.
// LDS: A [2][2 planes][64][128B] = 32 KB, B [2][2][32][128B] = 16 KB.
// 16B slots XOR-swizzled: phys = slot ^ (row&7) on both write and read.
struct Chunk { f32x4 a[4]; f32x4 b[2]; };

__global__ __launch_bounds__(512, 1) void fused_kernel(const float* __restrict__ x,
                                                       const float* __restrict__ w,
                                                       const float* __restrict__ bias,
                                                       float* __restrict__ out) {
    __shared__ signed char sA[2][16384];   // [buf][plane*8192 + row*128 + b]
    __shared__ signed char sB[2][8192];    // [buf][plane*4096 + row*128 + b]

    // XCD-ownership swizzle: XCD (bid&7) owns n-blocks 4x..4x+3 (128 W rows).
    int bid = blockIdx.x;
    int nblk = (bid & 7) * 4 + ((bid >> 3) & 3);
    int mblk = bid >> 5;
    int m0 = mblk * TM, n0 = nblk * TN;

    int t = threadIdx.x;
    int lane = t & 63;
    int wv = t >> 6;            // 8 waves: 4 m-quadrants x 2 n-quadrants
    int wm = wv >> 1, wn = wv & 1;

    // A: thread t -> row t>>3 (0..63), 16B-slot t&7 (16 f32).
    // B: thread t -> row t>>4 (0..31), 8B-half t&15 (8 f32).
    int aRow = t >> 3, aG = t & 7;
    int bRow = t >> 4, bG = t & 15;
    const float* aSrc = x + (size_t)(m0 + aRow) * IN_DIM + aG * 16;
    const float* bSrc = w + (size_t)(n0 + bRow) * IN_DIM + bG * 8;
    int aOff = aRow * 128 + ((aG ^ (aRow & 7)) * 16);
    int bOff = bRow * 128 + (((bG >> 1) ^ (bRow & 7)) * 16) + (bG & 1) * 8;

    auto loadc = [&](int c, Chunk& v) {
        const f32x4* pa = (const f32x4*)(aSrc + c * KC);
#pragma unroll
        for (int j = 0; j < 4; ++j) v.a[j] = pa[j];
        const f32x4* pb = (const f32x4*)(bSrc + c * KC);
#pragma unroll
        for (int j = 0; j < 2; ++j) v.b[j] = pb[j];
    };

    // magic-quant: t = RN(v*4096 + 2^23+2^22+128), ulp=1 half-even.
    // mantissa byte0 = (q+128)&255 -> ^0x80 = centered lo; byte1 = hi.
    const float MAGIC = 12583040.0f;       // 2^23 + 2^22 + 128
    auto writec = [&](int buf, Chunk& v) {
        unsigned int hwA[4], lwA[4];
#pragma unroll
        for (int j = 0; j < 4; ++j) {
            unsigned int tb[4];
#pragma unroll
            for (int e = 0; e < 4; ++e)
                tb[e] = __builtin_bit_cast(unsigned int, fmaf(v.a[j][e], 4096.0f, MAGIC));
            unsigned p01h = __builtin_amdgcn_perm(tb[1], tb[0], 0x00000501u);
            unsigned p23h = __builtin_amdgcn_perm(tb[3], tb[2], 0x00000501u);
            hwA[j] = __builtin_amdgcn_perm(p23h, p01h, 0x05040100u);
            unsigned p01l = __builtin_amdgcn_perm(tb[1], tb[0], 0x00000400u);
            unsigned p23l = __builtin_amdgcn_perm(tb[3], tb[2], 0x00000400u);
            lwA[j] = __builtin_amdgcn_perm(p23l, p01l, 0x05040100u) ^ 0x80808080u;
        }
        *(u32x4*)&sA[buf][aOff] = *(const u32x4*)hwA;          // plane0 = hi
        *(u32x4*)&sA[buf][8192 + aOff] = *(const u32x4*)lwA;   // plane1 = lo

        unsigned int hwB[2], lwB[2];
#pragma unroll
        for (int j = 0; j < 2; ++j) {
            unsigned int tb[4];
#pragma unroll
            for (int e = 0; e < 4; ++e)
                tb[e] = __builtin_bit_cast(unsigned int, fmaf(v.b[j][e], 4096.0f, MAGIC));
            unsigned p01h = __builtin_amdgcn_perm(tb[1], tb[0], 0x00000501u);
            unsigned p23h = __builtin_amdgcn_perm(tb[3], tb[2], 0x00000501u);
            hwB[j] = __builtin_amdgcn_perm(p23h, p01h, 0x05040100u);
            unsigned p01l = __builtin_amdgcn_perm(tb[1], tb[0], 0x00000400u);
            unsigned p23l = __builtin_amdgcn_perm(tb[3], tb[2], 0x00000400u);
            lwB[j] = __builtin_amdgcn_perm(p23l, p01l, 0x05040100u) ^ 0x80808080u;
        }
        *(u32x2*)&sB[buf][bOff] = *(const u32x2*)hwB;
        *(u32x2*)&sB[buf][4096 + bOff] = *(const u32x2*)lwB;
    };

    i32x4 hh = {}, mid = {}, ll = {};
    int arow = wm * 16 + (lane & 15);
    int brow = wn * 16 + (lane & 15);

    auto compute = [&](int buf) {
        __builtin_amdgcn_s_setprio(1);
#pragma unroll
        for (int k4 = 0; k4 < 2; ++k4) {
            int slot = ((k4 * 4 + (lane >> 4)) ^ (lane & 7)) * 16;  // arow&7==brow&7==lane&7
            i32x4 a0 = *(const i32x4*)&sA[buf][arow * 128 + slot];
            i32x4 a1 = *(const i32x4*)&sA[buf][8192 + arow * 128 + slot];
            i32x4 b0 = *(const i32x4*)&sB[buf][brow * 128 + slot];
            i32x4 b1 = *(const i32x4*)&sB[buf][4096 + brow * 128 + slot];
            hh  = __builtin_amdgcn_mfma_i32_16x16x64_i8(a0, b0, hh, 0, 0, 0);
            mid = __builtin_amdgcn_mfma_i32_16x16x64_i8(a0, b1, mid, 0, 0, 0);
            mid = __builtin_amdgcn_mfma_i32_16x16x64_i8(a1, b0, mid, 0, 0, 0);
            ll  = __builtin_amdgcn_mfma_i32_16x16x64_i8(a1, b1, ll, 0, 0, 0);
        }
        __builtin_amdgcn_s_setprio(0);
    };

    // ---- pipeline: depth-2 prefetch, write-late, 8 chunks ----
    Chunk v0, v1;
    loadc(0, v0);
    loadc(1, v1);
    writec(0, v0);
    __syncthreads();

#pragma unroll
    for (int c = 0; c < 8; ++c) {
        Chunk& vfree = (c & 1) ? v1 : v0;   // held chunk c (already in LDS)
        Chunk& vnext = (c & 1) ? v0 : v1;   // holds chunk c+1
        if (c < 6) loadc(c + 2, vfree);     // loads in flight across this phase
        compute(c & 1);
        if (c < 7) writec((c + 1) & 1, vnext);
        if (c < 7) __syncthreads();
    }

    // ---- epilogue: exact combine, integer round-half-even requantize, bias ----
    // round_he(s/4096): q=(s+2048)>>12 (floor, round-half-up); tie iff
    // (s&4095)==2048, then force even. Verified on +-0.5, +-1.5 ties.
    // C/D layout: col = lane&15, row = (lane>>4)*4 + j
    int grow0 = m0 + wm * 16 + ((lane >> 4) << 2);
    int gcol = n0 + wn * 16 + (lane & 15);
    float bv = bias[gcol];
#pragma unroll
    for (int j = 0; j < 4; ++j) {
        int s = hh[j] * 65536 + mid[j] * 256 + ll[j];   // exact int32 acc
        int q = (s + 2048) >> 12;
        q -= (((s & 4095) == 2048) & q) & 1;            // half-to-even tie fix
        q = q < -32768 ? -32768 : (q > 32767 ? 32767 : q);
        float r = (float)q * 0x1p-12f + bv;             // exact cvt + exact pow2 scale
        __builtin_nontemporal_store(r, &out[(size_t)(grow0 + j) * OUT_DIM + gcol]);
    }
}

extern "C" void kernel_launch(void* const* d_in, const int* in_sizes, int n_in,
                              void* d_out, int out_size, void* d_ws, size_t ws_size,
                              hipStream_t stream) {
    const float* x = (const float*)d_in[0];
    const float* w = (const float*)d_in[1];
    const float* bias = (const float*)d_in[2];
    float* out = (float*)d_out;

    fused_kernel<<<256, 512, 0, stream>>>(x, w, bias, out);
}

// Round 11
// 11.718 us; speedup vs baseline: 3.0681x; 1.0010x over previous
//
#include <hip/hip_runtime.h>
#include <stdint.h>

typedef int i32x4 __attribute__((ext_vector_type(4)));
typedef float f32x4 __attribute__((ext_vector_type(4)));
typedef unsigned int u32x2 __attribute__((ext_vector_type(2)));
typedef unsigned int u32x4 __attribute__((ext_vector_type(4)));

#define B_DIM 512
#define IN_DIM 1024
#define OUT_DIM 1024
#define TM 64
#define TN 32
#define KC 128          // original-k elements per chunk (8 chunks)

// Single fused kernel, 512 threads (8 waves), 256 blocks (1/CU, 2 waves/SIMD).
// f32 -> int16 -> hi/lo i8 planes via one magic-fma per element, byte-packed
// with v_perm, staged in XOR-swizzled double-buffered LDS, exact int8 MFMA
// GEMM (hh/mid/ll paths), exact integer requantize + bias.
//
// Schedule: 8 K-chunks, depth-2 register prefetch, quant/ds_write of chunk
// c+1 overlapped with MFMA of chunk c, s_setprio around MFMA clusters.
// LDS: A [2][2 planes][64][128B] = 32 KB, B [2][2][32][128B] = 16 KB.
// 16B slots XOR-swizzled: phys = slot ^ (row&7) on both write and read.
//
// XCD partition (2 m-groups x 4 n-groups): XCD k = 4*k_m + k_n owns
// mblk in [4*k_m, 4*k_m+4) x nblk in [8*k_n, 8*k_n+8) -> per-XCD L2 working
// set 1 MB x + 1 MB w; HBM first-touch 2MB*4 + 4MB*2 = 16 MB (was 20).
struct Chunk { f32x4 a[4]; f32x4 b[2]; };

__global__ __launch_bounds__(512, 1) void fused_kernel(const float* __restrict__ x,
                                                       const float* __restrict__ w,
                                                       const float* __restrict__ bias,
                                                       float* __restrict__ out) {
    __shared__ signed char sA[2][16384];   // [buf][plane*8192 + row*128 + b]
    __shared__ signed char sB[2][8192];    // [buf][plane*4096 + row*128 + b]

    int bid = blockIdx.x;
    int km = (bid & 7) >> 2;               // XCD m-group (0..1)
    int kn = bid & 3;                      // XCD n-group (0..3)
    int i = bid >> 3;                      // within-XCD index (0..31)
    int mblk = km * 4 + (i >> 3);
    int nblk = kn * 8 + (i & 7);
    int m0 = mblk * TM, n0 = nblk * TN;

    int t = threadIdx.x;
    int lane = t & 63;
    int wv = t >> 6;            // 8 waves: 4 m-quadrants x 2 n-quadrants
    int wm = wv >> 1, wn = wv & 1;

    // A: thread t -> row t>>3 (0..63), 16B-slot t&7 (16 f32).
    // B: thread t -> row t>>4 (0..31), 8B-half t&15 (8 f32).
    int aRow = t >> 3, aG = t & 7;
    int bRow = t >> 4, bG = t & 15;
    const float* aSrc = x + (size_t)(m0 + aRow) * IN_DIM + aG * 16;
    const float* bSrc = w + (size_t)(n0 + bRow) * IN_DIM + bG * 8;
    int aOff = aRow * 128 + ((aG ^ (aRow & 7)) * 16);
    int bOff = bRow * 128 + (((bG >> 1) ^ (bRow & 7)) * 16) + (bG & 1) * 8;

    auto loadc = [&](int c, Chunk& v) {
        const f32x4* pa = (const f32x4*)(aSrc + c * KC);
#pragma unroll
        for (int j = 0; j < 4; ++j) v.a[j] = pa[j];
        const f32x4* pb = (const f32x4*)(bSrc + c * KC);
#pragma unroll
        for (int j = 0; j < 2; ++j) v.b[j] = pb[j];
    };

    // magic-quant: t = RN(v*4096 + 2^23+2^22+128), ulp=1 half-even.
    // mantissa byte0 = (q+128)&255 -> ^0x80 = centered lo; byte1 = hi.
    const float MAGIC = 12583040.0f;       // 2^23 + 2^22 + 128
    auto writec = [&](int buf, Chunk& v) {
        unsigned int hwA[4], lwA[4];
#pragma unroll
        for (int j = 0; j < 4; ++j) {
            unsigned int tb[4];
#pragma unroll
            for (int e = 0; e < 4; ++e)
                tb[e] = __builtin_bit_cast(unsigned int, fmaf(v.a[j][e], 4096.0f, MAGIC));
            unsigned p01h = __builtin_amdgcn_perm(tb[1], tb[0], 0x00000501u);
            unsigned p23h = __builtin_amdgcn_perm(tb[3], tb[2], 0x00000501u);
            hwA[j] = __builtin_amdgcn_perm(p23h, p01h, 0x05040100u);
            unsigned p01l = __builtin_amdgcn_perm(tb[1], tb[0], 0x00000400u);
            unsigned p23l = __builtin_amdgcn_perm(tb[3], tb[2], 0x00000400u);
            lwA[j] = __builtin_amdgcn_perm(p23l, p01l, 0x05040100u) ^ 0x80808080u;
        }
        *(u32x4*)&sA[buf][aOff] = *(const u32x4*)hwA;          // plane0 = hi
        *(u32x4*)&sA[buf][8192 + aOff] = *(const u32x4*)lwA;   // plane1 = lo

        unsigned int hwB[2], lwB[2];
#pragma unroll
        for (int j = 0; j < 2; ++j) {
            unsigned int tb[4];
#pragma unroll
            for (int e = 0; e < 4; ++e)
                tb[e] = __builtin_bit_cast(unsigned int, fmaf(v.b[j][e], 4096.0f, MAGIC));
            unsigned p01h = __builtin_amdgcn_perm(tb[1], tb[0], 0x00000501u);
            unsigned p23h = __builtin_amdgcn_perm(tb[3], tb[2], 0x00000501u);
            hwB[j] = __builtin_amdgcn_perm(p23h, p01h, 0x05040100u);
            unsigned p01l = __builtin_amdgcn_perm(tb[1], tb[0], 0x00000400u);
            unsigned p23l = __builtin_amdgcn_perm(tb[3], tb[2], 0x00000400u);
            lwB[j] = __builtin_amdgcn_perm(p23l, p01l, 0x05040100u) ^ 0x80808080u;
        }
        *(u32x2*)&sB[buf][bOff] = *(const u32x2*)hwB;
        *(u32x2*)&sB[buf][4096 + bOff] = *(const u32x2*)lwB;
    };

    i32x4 hh = {}, mid = {}, ll = {};
    int arow = wm * 16 + (lane & 15);
    int brow = wn * 16 + (lane & 15);

    auto compute = [&](int buf) {
        __builtin_amdgcn_s_setprio(1);
#pragma unroll
        for (int k4 = 0; k4 < 2; ++k4) {
            int slot = ((k4 * 4 + (lane >> 4)) ^ (lane & 7)) * 16;  // arow&7==brow&7==lane&7
            i32x4 a0 = *(const i32x4*)&sA[buf][arow * 128 + slot];
            i32x4 a1 = *(const i32x4*)&sA[buf][8192 + arow * 128 + slot];
            i32x4 b0 = *(const i32x4*)&sB[buf][brow * 128 + slot];
            i32x4 b1 = *(const i32x4*)&sB[buf][4096 + brow * 128 + slot];
            hh  = __builtin_amdgcn_mfma_i32_16x16x64_i8(a0, b0, hh, 0, 0, 0);
            mid = __builtin_amdgcn_mfma_i32_16x16x64_i8(a0, b1, mid, 0, 0, 0);
            mid = __builtin_amdgcn_mfma_i32_16x16x64_i8(a1, b0, mid, 0, 0, 0);
            ll  = __builtin_amdgcn_mfma_i32_16x16x64_i8(a1, b1, ll, 0, 0, 0);
        }
        __builtin_amdgcn_s_setprio(0);
    };

    // ---- pipeline: depth-2 prefetch, write-late, 8 chunks ----
    Chunk v0, v1;
    loadc(0, v0);
    loadc(1, v1);
    writec(0, v0);
    __syncthreads();

#pragma unroll
    for (int c = 0; c < 8; ++c) {
        Chunk& vfree = (c & 1) ? v1 : v0;   // held chunk c (already in LDS)
        Chunk& vnext = (c & 1) ? v0 : v1;   // holds chunk c+1
        if (c < 6) loadc(c + 2, vfree);     // loads in flight across this phase
        compute(c & 1);
        if (c < 7) writec((c + 1) & 1, vnext);
        if (c < 7) __syncthreads();
    }

    // ---- epilogue: exact combine, integer round-half-even requantize, bias ----
    // round_he(s/4096): q=(s+2048)>>12 (floor, round-half-up); tie iff
    // (s&4095)==2048, then force even. Verified on +-0.5, +-1.5 ties.
    // C/D layout: col = lane&15, row = (lane>>4)*4 + j
    int grow0 = m0 + wm * 16 + ((lane >> 4) << 2);
    int gcol = n0 + wn * 16 + (lane & 15);
    float bv = bias[gcol];
#pragma unroll
    for (int j = 0; j < 4; ++j) {
        int s = hh[j] * 65536 + mid[j] * 256 + ll[j];   // exact int32 acc
        int q = (s + 2048) >> 12;
        q -= (((s & 4095) == 2048) & q) & 1;            // half-to-even tie fix
        q = q < -32768 ? -32768 : (q > 32767 ? 32767 : q);
        float r = (float)q * 0x1p-12f + bv;             // exact cvt + exact pow2 scale
        __builtin_nontemporal_store(r, &out[(size_t)(grow0 + j) * OUT_DIM + gcol]);
    }
}

extern "C" void kernel_launch(void* const* d_in, const int* in_sizes, int n_in,
                              void* d_out, int out_size, void* d_ws, size_t ws_size,
                              hipStream_t stream) {
    const float* x = (const float*)d_in[0];
    const float* w = (const float*)d_in[1];
    const float* bias = (const float*)d_in[2];
    float* out = (float*)d_out;

    fused_kernel<<<256, 512, 0, stream>>>(x, w, bias, out);
}